// Round 5
// baseline (1276.915 us; speedup 1.0000x reference)
//
#include <hip/hip_runtime.h>
#include <math.h>

#define B 64
#define T 128
#define D 256
#define H 256
#define G3 768   // 3*H
#define NCH 4    // blocks per batch
#define UC 64    // units per chunk
#define GC 192   // output columns per chunk (3 gates x 64 units)
#define TP 129   // hist row padding: (lane*129+j)%32 spreads lanes -> 2-way free
#define NTH 768  // 12 waves

// ---- workspace layout (bytes) ----
#define MX_OFF   0ull
#define MX_BYTES (8192ull * 768ull * 4ull)          // 25 165 824
#define HPUB_OFF (MX_OFF + MX_BYTES)
#define HPUB_BYTES (2ull * B * NCH * UC * 4ull)     // 131 072 (parity double-buffer)
#define FLAG_OFF (HPUB_OFF + HPUB_BYTES)            // 256 ints

// ---------------------------------------------------------------------------
// prep: zero the per-(batch,chunk) step flags (graph replays re-run this)
// ---------------------------------------------------------------------------
__global__ __launch_bounds__(256) void prep_kernel(char* __restrict__ ws) {
    int* flags = (int*)(ws + FLAG_OFF);
    if (threadIdx.x < B * NCH) flags[threadIdx.x] = 0;
}

// ---------------------------------------------------------------------------
// Kernel 1: MX[b,t,:] = inputs[b,t,:] @ kernel + bias[0]
// ---------------------------------------------------------------------------
__global__ __launch_bounds__(256) void mx_gemm_kernel(const float* __restrict__ x,
                                                      const float* __restrict__ K,
                                                      const float* __restrict__ bias,
                                                      float* __restrict__ MX) {
    __shared__ float xt[16][D];
    const int r0 = blockIdx.x * 16;
    const int tid = threadIdx.x;

    for (int idx = tid; idx < 16 * D; idx += 256) {
        xt[idx >> 8][idx & 255] = x[(size_t)(r0 + (idx >> 8)) * D + (idx & 255)];
    }
    __syncthreads();

    float acc0[16], acc1[16], acc2[16];
#pragma unroll
    for (int r = 0; r < 16; ++r) { acc0[r] = 0.f; acc1[r] = 0.f; acc2[r] = 0.f; }

    for (int d = 0; d < D; ++d) {
        float k0 = K[(size_t)d * G3 + tid];
        float k1 = K[(size_t)d * G3 + 256 + tid];
        float k2 = K[(size_t)d * G3 + 512 + tid];
#pragma unroll
        for (int r = 0; r < 16; ++r) {
            float xv = xt[r][d];
            acc0[r] += xv * k0;
            acc1[r] += xv * k1;
            acc2[r] += xv * k2;
        }
    }

    float b0 = bias[tid], b1 = bias[256 + tid], b2 = bias[512 + tid];
    for (int r = 0; r < 16; ++r) {
        size_t row = (size_t)(r0 + r) * G3;
        MX[row + tid]       = acc0[r] + b0;
        MX[row + 256 + tid] = acc1[r] + b1;
        MX[row + 512 + tid] = acc2[r] + b2;
    }
}

// ---------------------------------------------------------------------------
// Kernel 2: 4-block-per-batch GRU recurrence, fp32 R held in REGISTERS.
//   bid -> b = bid&63, k = bid>>6 (siblings share XCD under bid%8 round-robin).
//   thread -> col pair cp = tid%96 (local cols 2cp,2cp+1), row group q = tid/96
//   (rows 32q..32q+31); Rreg[32] float2 loaded once (fp32, static-indexed).
// Per step: S1 p1 (12-way j-split; wave 11 issues next-row prefetch loads)
//   | S2 wave0: hp reduce + publish + release flag | S3 waves0-2 spin+stage
//   siblings, wave 11 commits prefetch | S4 all: 64 reg-FMAs -> p2[8][GC]
//   | S5 wave0: reduce + gates -> hist + out.
// ---------------------------------------------------------------------------
__global__ __launch_bounds__(NTH) void rnn4_kernel(const float* __restrict__ cond,
                                                   const float* __restrict__ R,
                                                   const float* __restrict__ bias,
                                                   char* __restrict__ ws,
                                                   float* __restrict__ out) {
    const int bid = blockIdx.x;
    const int b   = bid & 63;
    const int k   = bid >> 6;
    const int tid = threadIdx.x;
    const int lane = tid & 63;
    const int wv   = tid >> 6;

    const float* MX = (const float*)(ws + MX_OFF);
    float* hpub = (float*)(ws + HPUB_OFF);
    int*   flags = (int*)(ws + FLAG_OFF);

    __shared__ float hist[UC][TP];                   // 33 024 B
    __shared__ __align__(16) float hpl[H];           //  1 024 B
    __shared__ float p1[12][UC];                     //  3 072 B
    __shared__ float p2[8][GC];                      //  6 144 B
    __shared__ float crow[2][T];                     //  1 024 B
    __shared__ float mxr[2][3][UC];                  //  1 536 B
    __shared__ float bias2[3][UC];                   //    768 B  -> 46 592 B

    // ---- one-time: R slice into registers (fp32, exact) ----
    const int cp = tid % 96;        // col pair -> local cols 2cp, 2cp+1
    const int q  = tid / 96;        // 0..7 -> rows 32q .. 32q+31
    float2 Rreg[32];
    {
        const int g0 = 2 * cp;      // local col, even; pair stays within a gate
        const int col0 = 256 * (g0 / 64) + UC * k + (g0 % 64);   // even
        const float* Rbase = R + col0;
#pragma unroll
        for (int rr = 0; rr < 32; ++rr) {
            Rreg[rr] = *reinterpret_cast<const float2*>(&Rbase[(size_t)(32 * q + rr) * G3]);
        }
    }

    // ---- init staging: bias2, crow[0] (row 1), mxr[0] (row 1) ----
    if (tid < GC) {
        bias2[tid / 64][tid % 64] = bias[G3 + 256 * (tid / 64) + UC * k + (tid % 64)];
    }
    if (tid >= 192 && tid < 320) {
        const int j = tid - 192;
        crow[0][j] = cond[((size_t)b * T + 1) * T + j];
    }
    if (tid >= 384 && tid < 576) {
        const int g = tid - 384, g3 = g / 64, u = g % 64;
        mxr[0][g3][u] = MX[((size_t)b * T + 1) * G3 + 256 * g3 + UC * k + u];
    }
    __syncthreads();

    // ---- step 0: h_prev = 0 -> mh = bias2 ----
    float hp_reg = 0.f;
    if (wv == 0) {
        const float* mx0 = &MX[(size_t)b * T * G3];
        const float xz = mx0[UC * k + lane];
        const float xr = mx0[256 + UC * k + lane];
        const float xh = mx0[512 + UC * k + lane];
        const float z = 1.f / (1.f + expf(-(xz + bias2[0][lane])));
        const float r = 1.f / (1.f + expf(-(xr + bias2[1][lane])));
        const float cand = tanhf(xh + r * bias2[2][lane]);
        const float hn = (1.f - z) * cand;
        hist[lane][0] = hn;
        out[(size_t)b * T * H + UC * k + lane] = hn;
    }

    for (int i = 1; i < T; ++i) {
        const int pb = (i - 1) & 1;
        const size_t pubbase = (((size_t)(i & 1) * B + b) * NCH) * UC;
        __syncthreads();                              // bar0: hist[i-1] + prefetches visible

        // ---- S1: p1 partials; wave 11 also issues next-row prefetch loads ----
        float pf_c0 = 0.f, pf_c1 = 0.f, pf_m0 = 0.f, pf_m1 = 0.f, pf_m2 = 0.f;
        if (wv == 11 && i + 1 < T) {
            const size_t csrc = ((size_t)b * T + (i + 1)) * T;
            pf_c0 = cond[csrc + lane];
            pf_c1 = cond[csrc + lane + 64];
            const size_t msrc = ((size_t)b * T + (i + 1)) * G3 + UC * k + lane;
            pf_m0 = MX[msrc];
            pf_m1 = MX[msrc + 256];
            pf_m2 = MX[msrc + 512];
        }
        {
            const int j0 = wv * 11;
            const int j1 = min(i, j0 + 11);
            float a = 0.f;
            for (int j = j0; j < j1; ++j) a += crow[pb][j] * hist[lane][j];
            p1[wv][lane] = a;
        }
        __syncthreads();                              // bar1

        // ---- S2: wave 0 reduces hp, publishes, releases flag ----
        if (wv == 0) {
            float hp = 0.f;
#pragma unroll
            for (int qq = 0; qq < 12; ++qq) hp += p1[qq][lane];
            hp_reg = hp;
            hpl[UC * k + lane] = hp;
            __hip_atomic_store(&hpub[pubbase + (size_t)k * UC + lane], hp,
                               __ATOMIC_RELAXED, __HIP_MEMORY_SCOPE_AGENT);
            if (tid == 0)
                __hip_atomic_store(&flags[b * NCH + k], i,
                                   __ATOMIC_RELEASE, __HIP_MEMORY_SCOPE_AGENT);
        }
        __syncthreads();                              // bar2

        // ---- S3: waves 0-2 spin + stage siblings; wave 11 commits prefetch ----
        if (wv < 3) {
            const int sib = (k + 1 + wv) & 3;
            while (__hip_atomic_load(&flags[b * NCH + sib],
                                     __ATOMIC_ACQUIRE, __HIP_MEMORY_SCOPE_AGENT) < i) {
                __builtin_amdgcn_s_sleep(1);
            }
            hpl[UC * sib + lane] =
                __hip_atomic_load(&hpub[pubbase + (size_t)sib * UC + lane],
                                  __ATOMIC_RELAXED, __HIP_MEMORY_SCOPE_AGENT);
        } else if (wv == 11 && i + 1 < T) {
            crow[i & 1][lane]      = pf_c0;
            crow[i & 1][lane + 64] = pf_c1;
            mxr[i & 1][0][lane] = pf_m0;
            mxr[i & 1][1][lane] = pf_m1;
            mxr[i & 1][2][lane] = pf_m2;
        }
        __syncthreads();                              // bar3: full hpl staged

        // ---- S4: mh partials, pure register FMA (fp32) ----
        {
            const float4* hv4 = reinterpret_cast<const float4*>(&hpl[32 * q]);
            float acc0 = 0.f, acc1 = 0.f;
#pragma unroll
            for (int m = 0; m < 8; ++m) {
                const float4 h = hv4[m];
                acc0 += h.x * Rreg[4 * m + 0].x + h.y * Rreg[4 * m + 1].x
                      + h.z * Rreg[4 * m + 2].x + h.w * Rreg[4 * m + 3].x;
                acc1 += h.x * Rreg[4 * m + 0].y + h.y * Rreg[4 * m + 1].y
                      + h.z * Rreg[4 * m + 2].y + h.w * Rreg[4 * m + 3].y;
            }
            *reinterpret_cast<float2*>(&p2[q][2 * cp]) = make_float2(acc0, acc1);
        }
        __syncthreads();                              // bar4

        // ---- S5: wave 0 reduces mh + gates ----
        if (wv == 0) {
            float mhz = bias2[0][lane], mhr = bias2[1][lane], mhh = bias2[2][lane];
#pragma unroll
            for (int qq = 0; qq < 8; ++qq) {
                mhz += p2[qq][lane];
                mhr += p2[qq][64 + lane];
                mhh += p2[qq][128 + lane];
            }
            const float xz = mxr[pb][0][lane];
            const float xr = mxr[pb][1][lane];
            const float xh = mxr[pb][2][lane];
            const float z = 1.f / (1.f + expf(-(xz + mhz)));
            const float r = 1.f / (1.f + expf(-(xr + mhr)));
            const float cand = tanhf(xh + r * mhh);
            const float hn = z * hp_reg + (1.f - z) * cand;
            hist[lane][i] = hn;
            out[((size_t)b * T + i) * H + UC * k + lane] = hn;
        }
    }
}

extern "C" void kernel_launch(void* const* d_in, const int* in_sizes, int n_in,
                              void* d_out, int out_size, void* d_ws, size_t ws_size,
                              hipStream_t stream) {
    const float* inputs     = (const float*)d_in[0];  // [B,T,D]
    const float* conditions = (const float*)d_in[1];  // [B,T,T]
    const float* kern       = (const float*)d_in[2];  // [D,3H]
    const float* rker       = (const float*)d_in[3];  // [H,3H]
    const float* bias       = (const float*)d_in[4];  // [2,3H]
    float* out = (float*)d_out;                       // [B,T,H]
    char* ws = (char*)d_ws;
    float* MX = (float*)(ws + MX_OFF);

    prep_kernel<<<1, 256, 0, stream>>>(ws);
    mx_gemm_kernel<<<(B * T) / 16, 256, 0, stream>>>(inputs, kern, bias, MX);
    rnn4_kernel<<<B * NCH, NTH, 0, stream>>>(conditions, rker, bias, ws, out);
}